// Round 5
// baseline (262.169 us; speedup 1.0000x reference)
//
#include <hip/hip_runtime.h>
#include <hip/hip_bf16.h>

// Round-5 restructure: 32x32x16 MFMA with A=W1 (M=hidden), B=x^T (N=edges).
// C/D layout (measured m74/m101): col=lane&31 -> EDGE, row=(reg&3)+8*(reg>>2)
// +4*(lane>>5) -> HIDDEN. So fc2's 256-wide reduction is 16 in-lane FMAs +
// ONE shfl_xor(32), replacing 64 ds_swizzle shuffles per wave-tile. b1 is
// folded into the MFMA accumulator init. No z pre-pass (r4 proved HBM-neutral).

#define N_EDGES 500000
#define D_IN    128
#define D_HID   256
#define M_TILE  32
#define NTILES  (N_EDGES / M_TILE)   // 15625 exactly
#define LDS_STRIDE 136               // 128 + 8 bf16 pad
#define GRID    1024

typedef __bf16 bf16x8 __attribute__((ext_vector_type(8)));
typedef float  f32x16 __attribute__((ext_vector_type(16)));
typedef float  f32x2  __attribute__((ext_vector_type(2)));

union F4H { float4 v; f32x2 h[2]; };

__device__ __forceinline__ unsigned int pkbf(f32x2 q) {
    union { __hip_bfloat162 b; unsigned int u; } c;
    c.b = __float22bfloat162_rn(make_float2(q.x, q.y));   // RNE packed cvt
    return c.u;
}

// mish(x) = x * N/(N+2), N = E*(E+2), E = e^x — exact identity, 2-wide
__device__ __forceinline__ f32x2 mish2(f32x2 x) {
    f32x2 xc = {fminf(x.x, 20.0f), fminf(x.y, 20.0f)};
    f32x2 E  = {__expf(xc.x), __expf(xc.y)};
    f32x2 num = E * (E + 2.0f);
    f32x2 den = num + 2.0f;
    f32x2 r  = {__builtin_amdgcn_rcpf(den.x), __builtin_amdgcn_rcpf(den.y)};
    return x * num * r;
}

__global__ __launch_bounds__(512, 4)
void edge_decoder_kernel(const float* __restrict__ z,
                         const int*   __restrict__ edge,
                         const float* __restrict__ W1,
                         const float* __restrict__ b1,
                         const float* __restrict__ W2,
                         const float* __restrict__ b2,
                         float*       __restrict__ out) {
    __shared__ ushort xbuf[2][M_TILE * LDS_STRIDE];   // 17.4 KB
    __shared__ float  lpart[2][8][M_TILE];            // 2 KB

    const int t    = threadIdx.x;
    const int wave = t >> 6;          // 0..7 -> hidden block [32w, 32w+32)
    const int lane = t & 63;
    const int half = lane >> 5;       // k-group within K=16
    const int col  = lane & 31;       // A: hidden row (m); B/D: edge (n)

    // ---- A-fragments: W1 rows for this wave's 32 hidden, f32 -> bf16, once ----
    // A[m][k]: m = col, k = kk*16 + half*8 + j
    bf16x8 afragW[8];
    {
        const float* wrow = W1 + (size_t)(wave * 32 + col) * D_IN;
        #pragma unroll
        for (int kk = 0; kk < 8; ++kk) {
            const float* wp = wrow + kk * 16 + half * 8;
            F4H w0{*reinterpret_cast<const float4*>(wp)};
            F4H w1{*reinterpret_cast<const float4*>(wp + 4)};
            union { unsigned int u[4]; bf16x8 v; } o;
            o.u[0] = pkbf(w0.h[0]); o.u[1] = pkbf(w0.h[1]);
            o.u[2] = pkbf(w1.h[0]); o.u[3] = pkbf(w1.h[1]);
            afragW[kk] = o.v;
        }
    }
    // ---- b1 (acc-init) and W2, in D-register layout ----
    float b1c[16], w2f[16];
    #pragma unroll
    for (int r = 0; r < 16; ++r) {
        const int n = wave * 32 + (r & 3) + 8 * (r >> 2) + 4 * half;
        b1c[r] = b1[n];
        w2f[r] = W2[n];
    }
    const float b2f = b2[0];

    const int s_slot = t >> 4;   // edge slot 0..31 (gather)
    const int cch    = t & 15;   // 8-float column chunk

    // ---- pipeline prologue ----
    int tile = blockIdx.x;
    float4 a0, a1, c0, c1;
    {
        const int e = tile * M_TILE + s_slot;
        const int u = edge[e], v = edge[N_EDGES + e];
        const float* zu = z + (size_t)u * D_IN + cch * 8;
        const float* zv = z + (size_t)v * D_IN + cch * 8;
        a0 = *reinterpret_cast<const float4*>(zu);
        a1 = *reinterpret_cast<const float4*>(zu + 4);
        c0 = *reinterpret_cast<const float4*>(zv);
        c1 = *reinterpret_cast<const float4*>(zv + 4);
    }
    int u_n, v_n;
    {
        const int t1 = min(tile + GRID, NTILES - 1);
        const int e1 = t1 * M_TILE + s_slot;
        u_n = edge[e1]; v_n = edge[N_EDGES + e1];
    }

    int  p = 0;
    bool have_prev = false;
    int  prev_base = 0;

    for (; tile < NTILES; tile += GRID) {
        // ---- A: convert current tile's rows -> xbuf[p] ----
        {
            F4H A0{a0}, A1{a1}, C0{c0}, C1{c1};
            *reinterpret_cast<uint4*>(&xbuf[p][s_slot * LDS_STRIDE + cch * 8]) =
                make_uint4(pkbf(A0.h[0] * C0.h[0]), pkbf(A0.h[1] * C0.h[1]),
                           pkbf(A1.h[0] * C1.h[0]), pkbf(A1.h[1] * C1.h[1]));
        }
        // ---- B: the single barrier ----
        __syncthreads();

        // ---- C: next tile's z loads + edge indices 2 tiles ahead ----
        {
            const float* zu = z + (size_t)u_n * D_IN + cch * 8;
            const float* zv = z + (size_t)v_n * D_IN + cch * 8;
            a0 = *reinterpret_cast<const float4*>(zu);
            a1 = *reinterpret_cast<const float4*>(zu + 4);
            c0 = *reinterpret_cast<const float4*>(zv);
            c1 = *reinterpret_cast<const float4*>(zv + 4);
        }
        {
            const int t2 = min(tile + 2 * GRID, NTILES - 1);
            const int e2 = t2 * M_TILE + s_slot;
            u_n = edge[e2]; v_n = edge[N_EDGES + e2];
        }

        // ---- E: combine + store PREVIOUS tile (sealed by barrier) ----
        if (have_prev && t < M_TILE) {
            const int pp = p ^ 1;
            float logit = b2f;
            #pragma unroll
            for (int w = 0; w < 8; ++w) logit += lpart[pp][w][t];
            out[prev_base + t] = __builtin_amdgcn_rcpf(1.0f + __expf(-logit));
        }

        // ---- D: 8x mfma_32x32x16, acc pre-loaded with b1 ----
        f32x16 acc;
        #pragma unroll
        for (int r = 0; r < 16; ++r) acc[r] = b1c[r];

        #pragma unroll
        for (int kk = 0; kk < 8; ++kk) {
            // B[k][n]: n = col (edge), k = kk*16 + half*8 + j
            bf16x8 bx = *reinterpret_cast<const bf16x8*>(
                &xbuf[p][col * LDS_STRIDE + kk * 16 + half * 8]);
            acc = __builtin_amdgcn_mfma_f32_32x32x16_bf16(afragW[kk], bx, acc, 0, 0, 0);
        }

        // ---- fc2: in-lane dot over 16 hidden regs, one cross-lane add ----
        float s = 0.f;
        #pragma unroll
        for (int r = 0; r < 16; r += 2) {
            f32x2 h = {acc[r], acc[r + 1]};      // bias already inside
            f32x2 m = mish2(h);
            s = fmaf(m.x, w2f[r], s);
            s = fmaf(m.y, w2f[r + 1], s);
        }
        s += __shfl_xor(s, 32);                  // combine the two k-halves' rows
        if (lane < 32) lpart[p][wave][col] = s;  // col == edge for lanes 0..31

        have_prev = true;
        prev_base = tile * M_TILE;
        p ^= 1;
    }

    // ---- drain ----
    __syncthreads();
    if (have_prev && t < M_TILE) {
        const int pp = p ^ 1;
        float logit = b2f;
        #pragma unroll
        for (int w = 0; w < 8; ++w) logit += lpart[pp][w][t];
        out[prev_base + t] = __builtin_amdgcn_rcpf(1.0f + __expf(-logit));
    }
}

extern "C" void kernel_launch(void* const* d_in, const int* in_sizes, int n_in,
                              void* d_out, int out_size, void* d_ws, size_t ws_size,
                              hipStream_t stream) {
    const float* z    = (const float*)d_in[0];
    const int*   edge = (const int*)d_in[1];
    const float* W1   = (const float*)d_in[2];
    const float* b1   = (const float*)d_in[3];
    const float* W2   = (const float*)d_in[4];
    const float* b2   = (const float*)d_in[5];
    float* out = (float*)d_out;

    edge_decoder_kernel<<<dim3(GRID), dim3(512), 0, stream>>>(z, edge, W1, b1, W2, b2, out);
}

// Round 6
// 179.950 us; speedup vs baseline: 1.4569x; 1.4569x over previous
//
#include <hip/hip_runtime.h>
#include <hip/hip_bf16.h>

// Round-6: r5 structure (32x32x16 MFMA, A=W1 M=hidden, B=x^T N=edges, fc2
// reduction in-lane + one shfl_xor(32), b1 folded into acc init) with the
// register budget FIXED: __launch_bounds__(512,2). r5's (512,4) was applied
// CUDA-style (4 blocks/CU) -> 64-VGPR cap -> scratch spills (WRITE_SIZE 92 MB,
// dur 193us). Working set is ~115 VGPRs; (512,2) gives a >=128 cap, no spill.

#define N_EDGES 500000
#define D_IN    128
#define D_HID   256
#define M_TILE  32
#define NTILES  (N_EDGES / M_TILE)   // 15625 exactly
#define LDS_STRIDE 136               // 128 + 8 bf16 pad (0 conflicts measured r5)
#define GRID    1024

typedef __bf16 bf16x8 __attribute__((ext_vector_type(8)));
typedef float  f32x16 __attribute__((ext_vector_type(16)));
typedef float  f32x2  __attribute__((ext_vector_type(2)));

union F4H { float4 v; f32x2 h[2]; };

__device__ __forceinline__ unsigned int pkbf(f32x2 q) {
    union { __hip_bfloat162 b; unsigned int u; } c;
    c.b = __float22bfloat162_rn(make_float2(q.x, q.y));   // RNE packed cvt
    return c.u;
}

// mish(x) = x * N/(N+2), N = E*(E+2), E = e^x — exact identity, 2-wide
__device__ __forceinline__ f32x2 mish2(f32x2 x) {
    f32x2 xc = {fminf(x.x, 20.0f), fminf(x.y, 20.0f)};
    f32x2 E  = {__expf(xc.x), __expf(xc.y)};
    f32x2 num = E * (E + 2.0f);
    f32x2 den = num + 2.0f;
    f32x2 r  = {__builtin_amdgcn_rcpf(den.x), __builtin_amdgcn_rcpf(den.y)};
    return x * num * r;
}

__global__ __launch_bounds__(512, 2)
void edge_decoder_kernel(const float* __restrict__ z,
                         const int*   __restrict__ edge,
                         const float* __restrict__ W1,
                         const float* __restrict__ b1,
                         const float* __restrict__ W2,
                         const float* __restrict__ b2,
                         float*       __restrict__ out) {
    __shared__ ushort xbuf[2][M_TILE * LDS_STRIDE];   // 17.4 KB
    __shared__ float  lpart[2][8][M_TILE];            // 2 KB

    const int t    = threadIdx.x;
    const int wave = t >> 6;          // 0..7 -> hidden block [32w, 32w+32)
    const int lane = t & 63;
    const int half = lane >> 5;       // k-group within K=16
    const int col  = lane & 31;       // A: hidden row (m); B/D: edge (n)

    // ---- A-fragments: W1 rows for this wave's 32 hidden, f32 -> bf16, once ----
    // A[m][k]: m = col, k = kk*16 + half*8 + j
    bf16x8 afragW[8];
    {
        const float* wrow = W1 + (size_t)(wave * 32 + col) * D_IN;
        #pragma unroll
        for (int kk = 0; kk < 8; ++kk) {
            const float* wp = wrow + kk * 16 + half * 8;
            F4H w0{*reinterpret_cast<const float4*>(wp)};
            F4H w1{*reinterpret_cast<const float4*>(wp + 4)};
            union { unsigned int u[4]; bf16x8 v; } o;
            o.u[0] = pkbf(w0.h[0]); o.u[1] = pkbf(w0.h[1]);
            o.u[2] = pkbf(w1.h[0]); o.u[3] = pkbf(w1.h[1]);
            afragW[kk] = o.v;
        }
    }
    // ---- b1 (acc-init) and W2, in D-register layout ----
    float b1c[16], w2f[16];
    #pragma unroll
    for (int r = 0; r < 16; ++r) {
        const int n = wave * 32 + (r & 3) + 8 * (r >> 2) + 4 * half;
        b1c[r] = b1[n];
        w2f[r] = W2[n];
    }
    const float b2f = b2[0];

    const int s_slot = t >> 4;   // edge slot 0..31 (gather)
    const int cch    = t & 15;   // 8-float column chunk

    // ---- pipeline prologue ----
    int tile = blockIdx.x;
    float4 a0, a1, c0, c1;
    {
        const int e = tile * M_TILE + s_slot;
        const int u = edge[e], v = edge[N_EDGES + e];
        const float* zu = z + (size_t)u * D_IN + cch * 8;
        const float* zv = z + (size_t)v * D_IN + cch * 8;
        a0 = *reinterpret_cast<const float4*>(zu);
        a1 = *reinterpret_cast<const float4*>(zu + 4);
        c0 = *reinterpret_cast<const float4*>(zv);
        c1 = *reinterpret_cast<const float4*>(zv + 4);
    }
    int u_n, v_n;
    {
        const int t1 = min(tile + GRID, NTILES - 1);
        const int e1 = t1 * M_TILE + s_slot;
        u_n = edge[e1]; v_n = edge[N_EDGES + e1];
    }

    int  p = 0;
    bool have_prev = false;
    int  prev_base = 0;

    for (; tile < NTILES; tile += GRID) {
        // ---- A: convert current tile's rows -> xbuf[p] ----
        {
            F4H A0{a0}, A1{a1}, C0{c0}, C1{c1};
            *reinterpret_cast<uint4*>(&xbuf[p][s_slot * LDS_STRIDE + cch * 8]) =
                make_uint4(pkbf(A0.h[0] * C0.h[0]), pkbf(A0.h[1] * C0.h[1]),
                           pkbf(A1.h[0] * C1.h[0]), pkbf(A1.h[1] * C1.h[1]));
        }
        // ---- B: the single barrier ----
        __syncthreads();

        // ---- C: next tile's z loads + edge indices 2 tiles ahead ----
        {
            const float* zu = z + (size_t)u_n * D_IN + cch * 8;
            const float* zv = z + (size_t)v_n * D_IN + cch * 8;
            a0 = *reinterpret_cast<const float4*>(zu);
            a1 = *reinterpret_cast<const float4*>(zu + 4);
            c0 = *reinterpret_cast<const float4*>(zv);
            c1 = *reinterpret_cast<const float4*>(zv + 4);
        }
        {
            const int t2 = min(tile + 2 * GRID, NTILES - 1);
            const int e2 = t2 * M_TILE + s_slot;
            u_n = edge[e2]; v_n = edge[N_EDGES + e2];
        }

        // ---- E: combine + store PREVIOUS tile (sealed by barrier) ----
        if (have_prev && t < M_TILE) {
            const int pp = p ^ 1;
            float logit = b2f;
            #pragma unroll
            for (int w = 0; w < 8; ++w) logit += lpart[pp][w][t];
            out[prev_base + t] = __builtin_amdgcn_rcpf(1.0f + __expf(-logit));
        }

        // ---- D: 8x mfma_32x32x16, acc pre-loaded with b1 ----
        f32x16 acc;
        #pragma unroll
        for (int r = 0; r < 16; ++r) acc[r] = b1c[r];

        #pragma unroll
        for (int kk = 0; kk < 8; ++kk) {
            // B[k][n]: n = col (edge), k = kk*16 + half*8 + j
            bf16x8 bx = *reinterpret_cast<const bf16x8*>(
                &xbuf[p][col * LDS_STRIDE + kk * 16 + half * 8]);
            acc = __builtin_amdgcn_mfma_f32_32x32x16_bf16(afragW[kk], bx, acc, 0, 0, 0);
        }

        // ---- fc2: in-lane dot over 16 hidden regs, one cross-lane add ----
        float s = 0.f;
        #pragma unroll
        for (int r = 0; r < 16; r += 2) {
            f32x2 h = {acc[r], acc[r + 1]};      // bias already inside
            f32x2 m = mish2(h);
            s = fmaf(m.x, w2f[r], s);
            s = fmaf(m.y, w2f[r + 1], s);
        }
        s += __shfl_xor(s, 32);                  // combine the two k-halves' rows
        if (lane < 32) lpart[p][wave][col] = s;  // col == edge for lanes 0..31

        have_prev = true;
        prev_base = tile * M_TILE;
        p ^= 1;
    }

    // ---- drain ----
    __syncthreads();
    if (have_prev && t < M_TILE) {
        const int pp = p ^ 1;
        float logit = b2f;
        #pragma unroll
        for (int w = 0; w < 8; ++w) logit += lpart[pp][w][t];
        out[prev_base + t] = __builtin_amdgcn_rcpf(1.0f + __expf(-logit));
    }
}

extern "C" void kernel_launch(void* const* d_in, const int* in_sizes, int n_in,
                              void* d_out, int out_size, void* d_ws, size_t ws_size,
                              hipStream_t stream) {
    const float* z    = (const float*)d_in[0];
    const int*   edge = (const int*)d_in[1];
    const float* W1   = (const float*)d_in[2];
    const float* b1   = (const float*)d_in[3];
    const float* W2   = (const float*)d_in[4];
    const float* b2   = (const float*)d_in[5];
    float* out = (float*)d_out;

    edge_decoder_kernel<<<dim3(GRID), dim3(512), 0, stream>>>(z, edge, W1, b1, W2, b2, out);
}